// Round 3
// baseline (527.072 us; speedup 1.0000x reference)
//
#include <hip/hip_runtime.h>

#define HW    16384   // 128*128
#define NCH   256     // C
#define NB    16      // batch
#define INTER 128

// ---------------------------------------------------------------------------
// All tensors are float32 (per the reference). Output: [16, 4, 128, 128] f32.
//   out[b,0] = gelu_exact(sum_c x[b,c,:,:] * W3[c])
//   out[b,1..3] = x[b, top3_channel_r, :, :]
// psum[b] (16 tiles x 256 ch f32 = 16 KB) lives inside d_out's channel-1 slot
// (64 KB in f32 mode); kernel C's gather overwrites it afterwards.
// ---------------------------------------------------------------------------
__device__ __forceinline__ float* psum_ptr(float* out, int b) {
    return out + (size_t)(b * 4 + 1) * HW;
}

// ---------------------------------------------------------------------------
// Kernel A: single fused pass over x (268 MB).
// grid (16 tiles, 16 b), 256 threads, 4 positions/thread (float4).
// ---------------------------------------------------------------------------
__global__ __launch_bounds__(256) void k_pool_x3(
    const float* __restrict__ x, const float* __restrict__ W3, float* out)
{
    const int tile = blockIdx.x;
    const int b    = blockIdx.y;
    const int tid  = threadIdx.x;

    __shared__ float w3f[NCH];
    __shared__ float wsum[4][NCH];
    w3f[tid] = W3[tid];
    __syncthreads();

    const int pos = tile * 1024 + tid * 4;
    const float* xb = x + (size_t)b * NCH * HW + pos;
    const int wave = tid >> 6, lane = tid & 63;

    float a0=0.f, a1=0.f, a2=0.f, a3=0.f;
    #pragma unroll 8
    for (int c = 0; c < NCH; ++c) {
        float4 v = *(const float4*)(xb + (size_t)c * HW);
        float w = w3f[c];
        a0 = fmaf(v.x, w, a0); a1 = fmaf(v.y, w, a1);
        a2 = fmaf(v.z, w, a2); a3 = fmaf(v.w, w, a3);
        float cs = (v.x + v.y) + (v.z + v.w);
        cs += __shfl_xor(cs, 1);
        cs += __shfl_xor(cs, 2);
        cs += __shfl_xor(cs, 4);
        cs += __shfl_xor(cs, 8);
        cs += __shfl_xor(cs, 16);
        cs += __shfl_xor(cs, 32);
        if (lane == 0) wsum[wave][c] = cs;
    }
    __syncthreads();

    float s = wsum[0][tid] + wsum[1][tid] + wsum[2][tid] + wsum[3][tid];
    psum_ptr(out, b)[tile * NCH + tid] = s;

    const float is2 = 0.70710678118654752440f;
    float4 g;
    g.x = 0.5f * a0 * (1.f + erff(a0 * is2));
    g.y = 0.5f * a1 * (1.f + erff(a1 * is2));
    g.z = 0.5f * a2 * (1.f + erff(a2 * is2));
    g.w = 0.5f * a3 * (1.f + erff(a3 * is2));
    *(float4*)(out + (size_t)b * 4 * HW + pos) = g;
}

// ---------------------------------------------------------------------------
// Kernel B: per-sample tiny MLP chain: p -> g/theta/phi -> f -> y -> wy
// 16 blocks (one per b), 256 threads.
// ---------------------------------------------------------------------------
__global__ __launch_bounds__(256) void k_mlp(
    const float* outbuf,   // to read psum slots
    const float* __restrict__ Wg, const float* __restrict__ bg,
    const float* __restrict__ Wt, const float* __restrict__ bt,
    const float* __restrict__ Wp, const float* __restrict__ bp,
    const float* __restrict__ Wf, const float* __restrict__ bfv,
    const float* __restrict__ Wz, const float* __restrict__ bz,
    float* __restrict__ p_out, float* __restrict__ wy_out)
{
    const int b = blockIdx.x, tid = threadIdx.x;
    __shared__ float sp[NCH];
    __shared__ float sg[INTER], sth[INTER], sph[INTER];
    __shared__ float red[NCH];
    __shared__ float sy[INTER];
    __shared__ float sf;

    const float* psum = outbuf + (size_t)(b * 4 + 1) * HW;
    float s = 0.f;
    #pragma unroll
    for (int t = 0; t < 16; ++t) s += psum[t * NCH + tid];
    float pv = s * (1.0f / 16384.0f);
    sp[tid] = pv;
    p_out[b * NCH + tid] = pv;
    __syncthreads();

    // three 128x256 matvecs against the pooled vector
    for (int j = tid; j < 3 * INTER; j += 256) {
        const float* Wrow; float bias; int i, which;
        if (j < INTER)        { i = j;           Wrow = Wg + i * NCH; bias = bg[i]; which = 0; }
        else if (j < 2*INTER) { i = j - INTER;   Wrow = Wt + i * NCH; bias = bt[i]; which = 1; }
        else                  { i = j - 2*INTER; Wrow = Wp + i * NCH; bias = bp[i]; which = 2; }
        float acc = bias;
        for (int k = 0; k < NCH; k += 4) {
            float4 q = *(const float4*)(Wrow + k);
            acc = fmaf(q.x, sp[k+0], acc);
            acc = fmaf(q.y, sp[k+1], acc);
            acc = fmaf(q.z, sp[k+2], acc);
            acc = fmaf(q.w, sp[k+3], acc);
        }
        if (which == 0) sg[i] = acc;
        else if (which == 1) sth[i] = acc;
        else sph[i] = acc;
    }
    __syncthreads();

    // f = relu(cat([theta, phi]) . Wf + bf)   (scalar, N=1)
    float cat = (tid < INTER) ? sth[tid] : sph[tid - INTER];
    red[tid] = cat * Wf[tid];
    __syncthreads();
    if (tid == 0) {
        float acc = bfv[0];
        for (int k = 0; k < NCH; ++k) acc += red[k];
        sf = fmaxf(acc, 0.f);
    }
    __syncthreads();
    if (tid < INTER) sy[tid] = sf * sg[tid];
    __syncthreads();

    // wy[c] = y . Wz[c] + bz[c]
    {
        const float* Wrow = Wz + tid * INTER;
        float acc = bz[tid];
        for (int k = 0; k < INTER; k += 4) {
            float4 q = *(const float4*)(Wrow + k);
            acc = fmaf(q.x, sy[k+0], acc);
            acc = fmaf(q.y, sy[k+1], acc);
            acc = fmaf(q.z, sy[k+2], acc);
            acc = fmaf(q.w, sy[k+3], acc);
        }
        wy_out[b * NCH + tid] = acc;
    }
}

// ---------------------------------------------------------------------------
// Kernel C: BatchNorm (batch stats) + residual + sigmoid + top-3 + gather.
// 16 blocks (one per b), 256 threads (thread == channel).
// Top-k: (score, idx) shuffles, lower index wins ties (lax.top_k semantics).
// Gathered channels copied bit-exact (float4).
// ---------------------------------------------------------------------------
__global__ __launch_bounds__(256) void k_bn_topk_gather(
    const float* __restrict__ wy, const float* __restrict__ p,
    const float* __restrict__ gamma, const float* __restrict__ beta,
    const float* __restrict__ x, float* __restrict__ out)
{
    const int b = blockIdx.x, tid = threadIdx.x;
    const int wave = tid >> 6, lane = tid & 63;
    __shared__ float wsc[4];
    __shared__ int   wid[4];
    __shared__ int   sel[3];

    float vv[16];
    float mu = 0.f;
    #pragma unroll
    for (int bb = 0; bb < 16; ++bb) { vv[bb] = wy[bb * NCH + tid]; mu += vv[bb]; }
    mu *= (1.f / 16.f);
    float var = 0.f;
    #pragma unroll
    for (int bb = 0; bb < 16; ++bb) { float d = vv[bb] - mu; var = fmaf(d, d, var); }
    var *= (1.f / 16.f);

    float bn = gamma[tid] * (vv[b] - mu) * rsqrtf(var + 1e-5f) + beta[tid];
    float z  = bn + p[b * NCH + tid];
    float sc = 1.f / (1.f + expf(-z));   // score for channel == tid

    for (int r = 0; r < 3; ++r) {
        float s = sc; int id = tid;
        #pragma unroll
        for (int m = 1; m <= 32; m <<= 1) {
            float so = __shfl_xor(s, m);
            int   io = __shfl_xor(id, m);
            if (so > s || (so == s && io < id)) { s = so; id = io; }
        }
        if (lane == 0) { wsc[wave] = s; wid[wave] = id; }
        __syncthreads();
        if (tid == 0) {
            float bs = wsc[0]; int bi = wid[0];
            for (int w = 1; w < 4; ++w)
                if (wsc[w] > bs || (wsc[w] == bs && wid[w] < bi)) { bs = wsc[w]; bi = wid[w]; }
            sel[r] = bi;
        }
        __syncthreads();
        if (tid == sel[r]) sc = -1e30f;   // exclude chosen channel
        __syncthreads();
    }

    // gather 3 channels, float4 = 16 B per load/store
    for (int r = 0; r < 3; ++r) {
        int ch = sel[r];
        const float4* src = (const float4*)(x + ((size_t)(b * NCH + ch)) * HW);
        float4*       dst = (float4*)(out + (size_t)b * 4 * HW + (size_t)(1 + r) * HW);
        for (int i = tid; i < HW / 4; i += 256) dst[i] = src[i];
    }
}

extern "C" void kernel_launch(void* const* d_in, const int* in_sizes, int n_in,
                              void* d_out, int out_size, void* d_ws, size_t ws_size,
                              hipStream_t stream)
{
    const float* x     = (const float*)d_in[0];
    const float* Wg    = (const float*)d_in[1];
    const float* bg    = (const float*)d_in[2];
    const float* Wt    = (const float*)d_in[3];
    const float* bt    = (const float*)d_in[4];
    const float* Wp    = (const float*)d_in[5];
    const float* bp    = (const float*)d_in[6];
    const float* Wf    = (const float*)d_in[7];
    const float* bfv   = (const float*)d_in[8];
    const float* Wz    = (const float*)d_in[9];
    const float* bz    = (const float*)d_in[10];
    const float* gamma = (const float*)d_in[11];
    const float* beta  = (const float*)d_in[12];
    const float* W3    = (const float*)d_in[13];
    float* out = (float*)d_out;

    // d_ws: wy[16][256] f32 | p[16][256] f32   (32 KB total)
    float* wy = (float*)d_ws;
    float* p  = wy + NB * NCH;

    k_pool_x3<<<dim3(16, 16), 256, 0, stream>>>(x, W3, out);
    k_mlp<<<NB, 256, 0, stream>>>(out, Wg, bg, Wt, bt, Wp, bp, Wf, bfv, Wz, bz, p, wy);
    k_bn_topk_gather<<<NB, 256, 0, stream>>>(wy, p, gamma, beta, x, out);
}

// Round 4
// 419.322 us; speedup vs baseline: 1.2570x; 1.2570x over previous
//
#include <hip/hip_runtime.h>

#define HW    16384   // 128*128
#define NCH   256     // C
#define NB    16      // batch
#define INTER 128
#define HW4   4096    // HW/4 (float4 units)

// Output: [16, 4, 128, 128] f32.
//   out[b,0]    = gelu_exact(sum_c x[b,c,:,:] * W3[c])
//   out[b,1..3] = x[b, top3_ch_r, :, :]
// psum[b] (16 KB) borrows d_out's channel-1 slot between kernels A and B
// (kernel D's gather overwrites it afterwards).

// ---------------------------------------------------------------------------
// Kernel A: fused pool + x3 pass over x (268 MB), software-pipelined.
// grid (16 tiles, 16 b), 256 threads, float4/thread, 8-channel reg batches,
// double-buffered so 8 KB/wave stays in flight across the shfl/LDS chain.
// ---------------------------------------------------------------------------
__global__ __launch_bounds__(256) void k_pool_x3(
    const float* __restrict__ x, const float* __restrict__ W3, float* out)
{
    const int tile = blockIdx.x;
    const int b    = blockIdx.y;
    const int tid  = threadIdx.x;
    const int wave = tid >> 6, lane = tid & 63;

    __shared__ float w3f[NCH];
    __shared__ float wsum[4][NCH];
    w3f[tid] = W3[tid];
    __syncthreads();

    const int p4 = tile * 256 + tid;                     // float4 index in image
    const float4* xb = (const float4*)x + (size_t)b * NCH * HW4 + p4;

    float4 bufA[8], bufB[8];
    float a0 = 0.f, a1 = 0.f, a2 = 0.f, a3 = 0.f;

    #pragma unroll
    for (int j = 0; j < 8; ++j) bufA[j] = xb[(size_t)j * HW4];

    #define PROCESS(BUF, CBASE)                                             \
        _Pragma("unroll")                                                   \
        for (int j = 0; j < 8; ++j) {                                       \
            const int c = (CBASE) + j;                                      \
            float4 v = BUF[j];                                              \
            float w = w3f[c];                                               \
            a0 = fmaf(v.x, w, a0); a1 = fmaf(v.y, w, a1);                   \
            a2 = fmaf(v.z, w, a2); a3 = fmaf(v.w, w, a3);                   \
            float cs = (v.x + v.y) + (v.z + v.w);                           \
            cs += __shfl_xor(cs, 1);                                        \
            cs += __shfl_xor(cs, 2);                                        \
            cs += __shfl_xor(cs, 4);                                        \
            cs += __shfl_xor(cs, 8);                                        \
            cs += __shfl_xor(cs, 16);                                       \
            cs += __shfl_xor(cs, 32);                                       \
            if (lane == 0) wsum[wave][c] = cs;                              \
        }

    for (int cb = 0; cb < 32; cb += 2) {
        #pragma unroll
        for (int j = 0; j < 8; ++j) bufB[j] = xb[(size_t)((cb + 1) * 8 + j) * HW4];
        PROCESS(bufA, cb * 8)
        if (cb + 2 < 32) {
            #pragma unroll
            for (int j = 0; j < 8; ++j) bufA[j] = xb[(size_t)((cb + 2) * 8 + j) * HW4];
        }
        PROCESS(bufB, (cb + 1) * 8)
    }
    #undef PROCESS

    __syncthreads();
    float s = wsum[0][tid] + wsum[1][tid] + wsum[2][tid] + wsum[3][tid];
    out[(size_t)(b * 4 + 1) * HW + tile * NCH + tid] = s;   // psum slot

    const float is2 = 0.70710678118654752440f;
    float4 g;
    g.x = 0.5f * a0 * (1.f + erff(a0 * is2));
    g.y = 0.5f * a1 * (1.f + erff(a1 * is2));
    g.z = 0.5f * a2 * (1.f + erff(a2 * is2));
    g.w = 0.5f * a3 * (1.f + erff(a3 * is2));
    ((float4*)out)[(size_t)b * 4 * HW4 + p4] = g;
}

// ---------------------------------------------------------------------------
// Kernel B: per-sample tiny MLP chain: p -> g/theta/phi -> f -> y -> wy
// 16 blocks (one per b), 256 threads.
// ---------------------------------------------------------------------------
__global__ __launch_bounds__(256) void k_mlp(
    const float* outbuf,
    const float* __restrict__ Wg, const float* __restrict__ bg,
    const float* __restrict__ Wt, const float* __restrict__ bt,
    const float* __restrict__ Wp, const float* __restrict__ bp,
    const float* __restrict__ Wf, const float* __restrict__ bfv,
    const float* __restrict__ Wz, const float* __restrict__ bz,
    float* __restrict__ p_out, float* __restrict__ wy_out)
{
    const int b = blockIdx.x, tid = threadIdx.x;
    __shared__ float sp[NCH];
    __shared__ float sg[INTER], sth[INTER], sph[INTER];
    __shared__ float red[NCH];
    __shared__ float sy[INTER];
    __shared__ float sf;

    const float* psum = outbuf + (size_t)(b * 4 + 1) * HW;
    float s = 0.f;
    #pragma unroll
    for (int t = 0; t < 16; ++t) s += psum[t * NCH + tid];
    float pv = s * (1.0f / 16384.0f);
    sp[tid] = pv;
    p_out[b * NCH + tid] = pv;
    __syncthreads();

    for (int j = tid; j < 3 * INTER; j += 256) {
        const float* Wrow; float bias; int i, which;
        if (j < INTER)        { i = j;           Wrow = Wg + i * NCH; bias = bg[i]; which = 0; }
        else if (j < 2*INTER) { i = j - INTER;   Wrow = Wt + i * NCH; bias = bt[i]; which = 1; }
        else                  { i = j - 2*INTER; Wrow = Wp + i * NCH; bias = bp[i]; which = 2; }
        float acc = bias;
        for (int k = 0; k < NCH; k += 4) {
            float4 q = *(const float4*)(Wrow + k);
            acc = fmaf(q.x, sp[k+0], acc);
            acc = fmaf(q.y, sp[k+1], acc);
            acc = fmaf(q.z, sp[k+2], acc);
            acc = fmaf(q.w, sp[k+3], acc);
        }
        if (which == 0) sg[i] = acc;
        else if (which == 1) sth[i] = acc;
        else sph[i] = acc;
    }
    __syncthreads();

    float cat = (tid < INTER) ? sth[tid] : sph[tid - INTER];
    red[tid] = cat * Wf[tid];
    __syncthreads();
    if (tid == 0) {
        float acc = bfv[0];
        for (int k = 0; k < NCH; ++k) acc += red[k];
        sf = fmaxf(acc, 0.f);
    }
    __syncthreads();
    if (tid < INTER) sy[tid] = sf * sg[tid];
    __syncthreads();

    {
        const float* Wrow = Wz + tid * INTER;
        float acc = bz[tid];
        for (int k = 0; k < INTER; k += 4) {
            float4 q = *(const float4*)(Wrow + k);
            acc = fmaf(q.x, sy[k+0], acc);
            acc = fmaf(q.y, sy[k+1], acc);
            acc = fmaf(q.z, sy[k+2], acc);
            acc = fmaf(q.w, sy[k+3], acc);
        }
        wy_out[b * NCH + tid] = acc;
    }
}

// ---------------------------------------------------------------------------
// Kernel C: BatchNorm (batch stats) + residual + sigmoid + top-3 selection.
// 16 blocks (one per b), 256 threads. Writes sel[b][3] to ws; NO gather here.
// ---------------------------------------------------------------------------
__global__ __launch_bounds__(256) void k_bn_topk(
    const float* __restrict__ wy, const float* __restrict__ p,
    const float* __restrict__ gamma, const float* __restrict__ beta,
    int* __restrict__ sel_out)
{
    const int b = blockIdx.x, tid = threadIdx.x;
    const int wave = tid >> 6, lane = tid & 63;
    __shared__ float wsc[4];
    __shared__ int   wid[4];
    __shared__ int   sel[3];

    float vv[16];
    float mu = 0.f;
    #pragma unroll
    for (int bb = 0; bb < 16; ++bb) { vv[bb] = wy[bb * NCH + tid]; mu += vv[bb]; }
    mu *= (1.f / 16.f);
    float var = 0.f;
    #pragma unroll
    for (int bb = 0; bb < 16; ++bb) { float d = vv[bb] - mu; var = fmaf(d, d, var); }
    var *= (1.f / 16.f);

    float bn = gamma[tid] * (vv[b] - mu) * rsqrtf(var + 1e-5f) + beta[tid];
    float z  = bn + p[b * NCH + tid];
    float sc = 1.f / (1.f + expf(-z));

    for (int r = 0; r < 3; ++r) {
        float s = sc; int id = tid;
        #pragma unroll
        for (int m = 1; m <= 32; m <<= 1) {
            float so = __shfl_xor(s, m);
            int   io = __shfl_xor(id, m);
            if (so > s || (so == s && io < id)) { s = so; id = io; }
        }
        if (lane == 0) { wsc[wave] = s; wid[wave] = id; }
        __syncthreads();
        if (tid == 0) {
            float bs = wsc[0]; int bi = wid[0];
            for (int w = 1; w < 4; ++w)
                if (wsc[w] > bs || (wsc[w] == bs && wid[w] < bi)) { bs = wsc[w]; bi = wid[w]; }
            sel[r] = bi;
        }
        __syncthreads();
        if (tid == sel[r]) sc = -1e30f;
        __syncthreads();
    }
    if (tid < 3) sel_out[b * 3 + tid] = sel[tid];
}

// ---------------------------------------------------------------------------
// Kernel D: gather top-3 channels, spread over 192 blocks (4 seg x 3 r x 16 b)
// 16 KB copied per block, float4, bit-exact.
// ---------------------------------------------------------------------------
__global__ __launch_bounds__(256) void k_gather(
    const float* __restrict__ x, const int* __restrict__ sel,
    float* __restrict__ out)
{
    const int seg = blockIdx.x;   // 4
    const int r   = blockIdx.y;   // 3
    const int b   = blockIdx.z;   // 16
    const int ch  = sel[b * 3 + r];
    const float4* src = (const float4*)x + (size_t)(b * NCH + ch) * HW4 + seg * 1024;
    float4*       dst = (float4*)out + (size_t)(b * 4 + 1 + r) * HW4 + seg * 1024;
    #pragma unroll
    for (int i = 0; i < 4; ++i)
        dst[i * 256 + threadIdx.x] = src[i * 256 + threadIdx.x];
}

extern "C" void kernel_launch(void* const* d_in, const int* in_sizes, int n_in,
                              void* d_out, int out_size, void* d_ws, size_t ws_size,
                              hipStream_t stream)
{
    const float* x     = (const float*)d_in[0];
    const float* Wg    = (const float*)d_in[1];
    const float* bg    = (const float*)d_in[2];
    const float* Wt    = (const float*)d_in[3];
    const float* bt    = (const float*)d_in[4];
    const float* Wp    = (const float*)d_in[5];
    const float* bp    = (const float*)d_in[6];
    const float* Wf    = (const float*)d_in[7];
    const float* bfv   = (const float*)d_in[8];
    const float* Wz    = (const float*)d_in[9];
    const float* bz    = (const float*)d_in[10];
    const float* gamma = (const float*)d_in[11];
    const float* beta  = (const float*)d_in[12];
    const float* W3    = (const float*)d_in[13];
    float* out = (float*)d_out;

    // d_ws: wy[16][256] f32 | p[16][256] f32 | sel[16][3] int
    float* wy  = (float*)d_ws;
    float* p   = wy + NB * NCH;
    int*   sel = (int*)(p + NB * NCH);

    k_pool_x3<<<dim3(16, 16), 256, 0, stream>>>(x, W3, out);
    k_mlp<<<NB, 256, 0, stream>>>(out, Wg, bg, Wt, bt, Wp, bp, Wf, bfv, Wz, bz, p, wy);
    k_bn_topk<<<NB, 256, 0, stream>>>(wy, p, gamma, beta, sel);
    k_gather<<<dim3(4, 3, NB), 256, 0, stream>>>(x, sel, out);
}